// Round 9
// baseline (808.069 us; speedup 1.0000x reference)
//
#include <hip/hip_runtime.h>
#include <stdint.h>

#define N_NODES 100000
#define N_PAD   100032            // 1563 * 64, padded rows for MFMA GEMM
#define N_EDGES 1600000
#define DIM 128
#define NLAYERS 4
#define NGRAPH 128
#define NCLS 10
#define EPSV 1e-5f
#define NSLOT 32                  // fixed padded slots per node (P(deg>32) ~ 3e-5)
#define POOL_PARTS 8              // blocks per graph in k_norm_pool
#define NTILE (N_PAD / 64)        // 1563 GEMM row-tiles
#define GEMM_GRID 782             // persistent blocks; 2 tiles per block, pipelined

#define BIN_SHIFT 9
#define NBUCKET ((N_NODES + 511) >> 9)              // 196
#define P1_EPB 4096
#define P1_BLOCKS ((N_EDGES + P1_EPB - 1) / P1_EPB) // 391

typedef __attribute__((ext_vector_type(8))) short short8_t;   // 8 bf16
typedef __attribute__((ext_vector_type(4))) float float4_t;   // 4 fp32 acc

// ---------------- bf16 / int8 helpers ----------------

__device__ __forceinline__ float bf_lo(uint32_t u) { return __uint_as_float(u << 16); }
__device__ __forceinline__ float bf_hi(uint32_t u) { return __uint_as_float(u & 0xffff0000u); }
__device__ __forceinline__ uint32_t f2bf_rne(float f) {
    uint32_t x = __float_as_uint(f);
    return (x + 0x7fffu + ((x >> 16) & 1u)) >> 16;
}
__device__ __forceinline__ uint32_t pack_bf2(float a, float b) {
    return f2bf_rne(a) | (f2bf_rne(b) << 16);
}
__device__ __forceinline__ float4 unpack4(uint2 u) {
    return make_float4(bf_lo(u.x), bf_hi(u.x), bf_lo(u.y), bf_hi(u.y));
}
// these compile to v_cvt_f32_ubyte{0..3} (single VALU op each)
__device__ __forceinline__ float ub0(uint32_t u) { return (float)( u        & 0xffu); }
__device__ __forceinline__ float ub1(uint32_t u) { return (float)((u >>  8) & 0xffu); }
__device__ __forceinline__ float ub2(uint32_t u) { return (float)((u >> 16) & 0xffu); }
__device__ __forceinline__ float ub3(uint32_t u) { return (float)( u >> 24        ); }
// fast ELU negative branch: exp(x)-1 via v_exp_f32 (tolerance-safe vs expm1f)
__device__ __forceinline__ float elu_neg(float x) { return __expf(x) - 1.f; }

// ---------------- prepass kernels ----------------

// graph boundaries from SORTED batch (no atomics); zero bucket counters + pooled
__global__ void k_node_meta(const int* __restrict__ batch, int* __restrict__ gstart,
                            int* __restrict__ bcnt, float* __restrict__ pooled) {
    int i = blockIdx.x * blockDim.x + threadIdx.x;
    if (i < NBUCKET) bcnt[i] = 0;
    if (i < NGRAPH * DIM) pooled[i] = 0.f;
    if (i >= N_NODES) return;
    int b = batch[i];
    if (i == 0) {
        for (int g = 0; g <= b; g++) gstart[g] = 0;
    } else {
        int bp = batch[i - 1];
        for (int g = bp + 1; g <= b; g++) gstart[g] = i;
    }
    if (i == N_NODES - 1) {
        for (int g = b + 1; g <= NGRAPH; g++) gstart[g] = N_NODES;
    }
}

// histogram edges by dst bucket
__global__ __launch_bounds__(256) void k_bhist(const int* __restrict__ ei, int* __restrict__ bcnt) {
    __shared__ int hist[NBUCKET];
    int t = threadIdx.x;
    for (int i = t; i < NBUCKET; i += 256) hist[i] = 0;
    __syncthreads();
    int e0 = blockIdx.x * P1_EPB;
    int e1 = e0 + P1_EPB; if (e1 > N_EDGES) e1 = N_EDGES;
    for (int e = e0 + t; e < e1; e += 256) atomicAdd(&hist[ei[N_EDGES + e] >> BIN_SHIFT], 1);
    __syncthreads();
    for (int i = t; i < NBUCKET; i += 256) if (hist[i]) atomicAdd(&bcnt[i], hist[i]);
}

// exclusive scan of bucket counts -> bucket_off[0..NBUCKET]; init bcur
__global__ __launch_bounds__(256) void k_bscan(const int* __restrict__ bcnt,
                                               int* __restrict__ bucket_off, int* __restrict__ bcur) {
    __shared__ int s[256];
    int t = threadIdx.x;
    int v = (t < NBUCKET) ? bcnt[t] : 0;
    s[t] = v; __syncthreads();
    for (int off = 1; off < 256; off <<= 1) {
        int a = (t >= off) ? s[t - off] : 0;
        __syncthreads();
        s[t] += a;
        __syncthreads();
    }
    if (t < NBUCKET) { bucket_off[t] = s[t] - v; bcur[t] = s[t] - v; }
    if (t == 0) bucket_off[NBUCKET] = s[255];
}

// pass 1: bin edges by dst bucket (append-sequential writes per bucket)
__global__ __launch_bounds__(256) void k_bin_edges(const int* __restrict__ ei,
                                                   int* __restrict__ bcur,
                                                   int2* __restrict__ binned) {
    __shared__ int hist[NBUCKET];
    __shared__ int base[NBUCKET];
    int t = threadIdx.x;
    int e0 = blockIdx.x * P1_EPB;
    int e1 = e0 + P1_EPB; if (e1 > N_EDGES) e1 = N_EDGES;
    for (int i = t; i < NBUCKET; i += 256) hist[i] = 0;
    __syncthreads();
    int myrank[P1_EPB / 256];
    int cnt = 0;
    for (int e = e0 + t; e < e1; e += 256) {
        int d = ei[N_EDGES + e];
        myrank[cnt++] = atomicAdd(&hist[d >> BIN_SHIFT], 1);
    }
    __syncthreads();
    for (int i = t; i < NBUCKET; i += 256) base[i] = atomicAdd(&bcur[i], hist[i]);
    __syncthreads();
    cnt = 0;
    for (int e = e0 + t; e < e1; e += 256) {
        int s = ei[e];
        int d = ei[N_EDGES + e];
        binned[base[d >> BIN_SHIFT] + myrank[cnt++]] = make_int2(s, d);
    }
}

// per-bucket: histogram dst -> local scan -> rowoff + dis; sentinel-pad psrc slots.
// FIRST pad slot of each node with deg < NSLOT is the node ITSELF: its weight
// dd*hsd[n] = dis^2 * qscale is exactly the GCN self-loop term.
__global__ __launch_bounds__(256) void k_bucket_build(const int2* __restrict__ binned,
                                                      const int* __restrict__ bucket_off,
                                                      int* __restrict__ rowoff,
                                                      float* __restrict__ dis,
                                                      int* __restrict__ psrc) {
    __shared__ int cnt[512];
    __shared__ int sa[512];
    __shared__ int sb[512];
    int b = blockIdx.x;
    int t = threadIdx.x;
    int n0 = b << BIN_SHIFT;
    int j0 = bucket_off[b], j1 = bucket_off[b + 1];
    cnt[t] = 0; cnt[t + 256] = 0;
    __syncthreads();
    for (int j = j0 + t; j < j1; j += 256) atomicAdd(&cnt[binned[j].y & 511], 1);
    __syncthreads();
    sa[t] = cnt[t]; sa[t + 256] = cnt[t + 256];
    __syncthreads();
    int* A = sa; int* B = sb;
    for (int off = 1; off < 512; off <<= 1) {
        int i0 = t, i1 = t + 256;
        B[i0] = A[i0] + ((i0 >= off) ? A[i0 - off] : 0);
        B[i1] = A[i1] + ((i1 >= off) ? A[i1 - off] : 0);
        __syncthreads();
        int* tmp = A; A = B; B = tmp;
    }
    // A = inclusive scan
    for (int i = t; i < 512; i += 256) {
        int n = n0 + i;
        if (n < N_NODES) {
            rowoff[n] = j0 + A[i] - cnt[i];
            dis[n] = rsqrtf((float)(1 + cnt[i]));
        }
    }
    if (b == NBUCKET - 1 && t == 0) rowoff[N_NODES] = N_EDGES;
    // pad slots: slot cnt = SELF; slots > cnt = sentinel (hsd[N_NODES] == 0)
    for (int idx = t; idx < 512 * NSLOT; idx += 256) {
        int i = idx >> 5, k = idx & (NSLOT - 1);
        int n = n0 + i;
        if (n < N_NODES && k >= cnt[i]) psrc[(size_t)n * NSLOT + k] = (k == cnt[i]) ? n : N_NODES;
    }
}

// pass 2: one block per bucket; scatter within the bucket's L2-resident window.
// writes full csc (for rare deg>=32 overflow) and first-32 padded psrc slots.
__global__ __launch_bounds__(256) void k_scatter(const int2* __restrict__ binned,
                                                 const float* __restrict__ dis,
                                                 const int* __restrict__ rowoff,
                                                 const int* __restrict__ bucket_off,
                                                 int2* __restrict__ csc,
                                                 int* __restrict__ psrc) {
    __shared__ int lcur[512];
    int b = blockIdx.x;
    int t = threadIdx.x;
    lcur[t] = 0; lcur[t + 256] = 0;
    __syncthreads();
    int j0 = bucket_off[b], j1 = bucket_off[b + 1];
    for (int j = j0 + t; j < j1; j += 256) {
        int2 sd = binned[j];
        float w = dis[sd.x] * dis[sd.y];
        int rank = atomicAdd(&lcur[sd.y & 511], 1);
        csc[rowoff[sd.y] + rank] = make_int2(sd.x, __float_as_int(w));
        if (rank < NSLOT) psrc[(size_t)sd.y * NSLOT + rank] = sd.x;
    }
}

// cast conv_w (fp32, [L][K][N]) -> Wt (bf16, [L][N][K] packed as uint pairs along K)
__global__ void k_cast_w(const float* __restrict__ W, uint32_t* __restrict__ Wt) {
    int i = blockIdx.x * blockDim.x + threadIdx.x;    // over L*128*64
    if (i >= NLAYERS * DIM * 64) return;
    int l = i / (DIM * 64);
    int n = (i / 64) % DIM;
    int ku = i % 64;
    const float* Wl = W + (size_t)l * DIM * DIM;
    float w0 = Wl[(2 * ku) * DIM + n];
    float w1 = Wl[(2 * ku + 1) * DIM + n];
    Wt[i] = pack_bf2(w0, w1);
}

// ---------------- GEMM cores ----------------

// MFMA phase: A-tile in LDS (uint [64][68], bf16 pairs), B = Wt global.
// Per-row amax computed IN-REGISTER from MFMA accumulators, quantized
// in-register, int8 bytes bounced through a small LDS tile for coalesced stores.
__device__ __forceinline__ void gemm_phase(const uint32_t (*atile)[68], const uint32_t* __restrict__ Wt,
                                           uint8_t (*ctile8)[132], float* rmaxl,
                                           uint8_t* __restrict__ H8,
                                           float* __restrict__ hsd, const float* __restrict__ dis,
                                           int blk, int t) {
    int wid = t >> 6;
    int lane = t & 63;
    int quad = lane >> 4;
    int s15 = lane & 15;

    float4_t acc[8];
#pragma unroll
    for (int i = 0; i < 8; i++) acc[i] = (float4_t){0.f, 0.f, 0.f, 0.f};

#pragma unroll
    for (int kk = 0; kk < 4; kk++) {
        uint4 au = *(const uint4*)&atile[wid * 16 + s15][quad * 4 + kk * 16];
        short8_t a = __builtin_bit_cast(short8_t, au);
#pragma unroll
        for (int nt = 0; nt < 8; nt++) {
            uint4 bu = *(const uint4*)(Wt + (size_t)(nt * 16 + s15) * 64 + kk * 16 + quad * 4);
            short8_t b = __builtin_bit_cast(short8_t, bu);
            acc[nt] = __builtin_amdgcn_mfma_f32_16x16x32_bf16(a, b, acc[nt], 0, 0, 0);
        }
    }
    __syncthreads();       // A-tile dead; reuse LDS for int8 C + rmax

    // per-row amax: rows of this quad are wid*16+quad*4+r; reduce over 16 s15 lanes
    float sinv[4];
#pragma unroll
    for (int r = 0; r < 4; r++) {
        float m = fabsf(acc[0][r]);
#pragma unroll
        for (int nt = 1; nt < 8; nt++) m = fmaxf(m, fabsf(acc[nt][r]));
        m = fmaxf(m, __shfl_xor(m, 1));
        m = fmaxf(m, __shfl_xor(m, 2));
        m = fmaxf(m, __shfl_xor(m, 4));
        m = fmaxf(m, __shfl_xor(m, 8));
        if (s15 == 0) rmaxl[wid * 16 + quad * 4 + r] = m;
        sinv[r] = (m > 0.f) ? 127.f / m : 0.f;
    }
    // quantize in-register, write bytes to LDS
#pragma unroll
    for (int nt = 0; nt < 8; nt++) {
#pragma unroll
        for (int r = 0; r < 4; r++) {
            int qv = (int)fmaf(acc[nt][r], sinv[r], 128.5f);   // in [1,255]
            ctile8[wid * 16 + quad * 4 + r][nt * 16 + s15] = (uint8_t)qv;
        }
    }
    __syncthreads();
    uint8_t* Hb = H8 + (size_t)blk * 64 * 128;
    float* Hsb = hsd + (size_t)blk * 64;
#pragma unroll
    for (int i = 0; i < 8; i++) {
        int idx = t + 256 * i;            // 2048 uints (64 rows x 32)
        int row = idx >> 5, cu = idx & 31;
        uint32_t v = *(const uint32_t*)&ctile8[row][cu * 4];
        ((uint32_t*)Hb)[(size_t)row * 32 + cu] = v;
        if (cu == 0) {
            size_t gr = (size_t)blk * 64 + row;
            float dv = (gr < N_NODES) ? dis[gr] : 0.f;   // pad rows -> 0 weight
            Hsb[row] = rmaxl[row] * (1.f / 127.f) * dv;
        }
    }
}

#define GEMM_SMEM \
    __shared__ __align__(16) char smem[64 * 68 * 4]; \
    uint32_t (*atile)[68] = (uint32_t(*)[68])smem; \
    uint8_t (*ctile8)[132] = (uint8_t(*)[132])smem; \
    float* rmaxl = (float*)(smem + 64 * 132);

// layer-0 GEMM, persistent/pipelined: 2 tiles per block; next tile's X loads
// are issued into registers BEFORE the current tile's MFMA+epilogue, so HBM
// latency hides under compute and stage/compute phases overlap across tiles.
__global__ __launch_bounds__(256) void k_gemm0(const float* __restrict__ X, const uint32_t* __restrict__ Wt,
                                               uint8_t* __restrict__ H8, float* __restrict__ hsd,
                                               const float* __restrict__ dis) {
    GEMM_SMEM
    int t = threadIdx.x;
    float4 pf[8];
    int tile = blockIdx.x;
    auto prefetch = [&](int tl) {
#pragma unroll
        for (int i = 0; i < 8; i++) {
            int idx = t + 256 * i;        // 2048 float4-groups
            int row = idx >> 5, q = idx & 31;
            size_t gr = (size_t)tl * 64 + row;
            pf[i] = (gr < N_NODES) ? ((const float4*)(X + gr * DIM))[q]
                                   : make_float4(0.f, 0.f, 0.f, 0.f);
        }
    };
    prefetch(tile);
    while (tile < NTILE) {
        int cur = tile;
        tile += GEMM_GRID;
#pragma unroll
        for (int i = 0; i < 8; i++) {
            int idx = t + 256 * i;
            int row = idx >> 5, q = idx & 31;
            uint2 p;
            p.x = pack_bf2(pf[i].x, pf[i].y);
            p.y = pack_bf2(pf[i].z, pf[i].w);
            *(uint2*)&atile[row][q * 2] = p;
        }
        __syncthreads();
        if (tile < NTILE) prefetch(tile);     // in flight during MFMA+epilogue
        gemm_phase(atile, Wt, ctile8, rmaxl, H8, hsd, dis, cur, t);
        __syncthreads();                      // LDS (ctile8) reads drained before reuse
    }
}

// fused GraphNorm+ELU+residual (layer l) + GEMM (layer l+1), persistent/pipelined.
// A = agg in bf16; residual in fp32 (layer 0) or bf16 (layers 1,2); writes bf16 residual out.
template <bool RBF>
__global__ __launch_bounds__(256) void k_norm_gemm(const uint32_t* __restrict__ A, const int* __restrict__ batch,
                                                   const float* __restrict__ amean, const float* __restrict__ rstd,
                                                   const float* __restrict__ gw, const float* __restrict__ gb,
                                                   const void* __restrict__ res, uint32_t* __restrict__ res_out,
                                                   const uint32_t* __restrict__ Wt,
                                                   uint8_t* __restrict__ H8, float* __restrict__ hsd,
                                                   const float* __restrict__ dis) {
    GEMM_SMEM
    int t = threadIdx.x;
    uint2 pa[8];          // agg rows
    uint2 pr2[8];         // bf16 residual (RBF)
    float4 pr4[8];        // fp32 residual (!RBF)
    int   pg[8];          // graph ids
    int tile = blockIdx.x;
    auto prefetch = [&](int tl) {
#pragma unroll
        for (int i = 0; i < 8; i++) {
            int idx = t + 256 * i;
            int row = idx >> 5, q = idx & 31;
            size_t gr = (size_t)tl * 64 + row;
            if (gr < N_NODES) {
                pg[i] = batch[gr];
                pa[i] = ((const uint2*)(A + gr * 64))[q];
                if (RBF) pr2[i] = ((const uint2*)((const uint32_t*)res + gr * 64))[q];
                else     pr4[i] = ((const float4*)res)[gr * 32 + q];
            } else {
                pg[i] = 0;
                pa[i] = make_uint2(0u, 0u);
                if (RBF) pr2[i] = make_uint2(0u, 0u);
                else     pr4[i] = make_float4(0.f, 0.f, 0.f, 0.f);
            }
        }
    };
    prefetch(tile);
    while (tile < NTILE) {
        int cur = tile;
        tile += GEMM_GRID;
#pragma unroll
        for (int i = 0; i < 8; i++) {
            int idx = t + 256 * i;
            int row = idx >> 5, q = idx & 31;
            size_t gr = (size_t)cur * 64 + row;
            uint2 p = make_uint2(0u, 0u);
            if (gr < N_NODES) {
                int g = pg[i];
                float4 v = unpack4(pa[i]);
                float4 am = ((const float4*)amean)[g * 32 + q];
                float4 rs = ((const float4*)rstd)[g * 32 + q];
                float4 w = ((const float4*)gw)[q];
                float4 b = ((const float4*)gb)[q];
                float4 r;
                if (RBF) r = unpack4(pr2[i]);
                else     r = pr4[i];
                float4 o;
                o.x = w.x * (v.x - am.x) * rs.x + b.x;
                o.y = w.y * (v.y - am.y) * rs.y + b.y;
                o.z = w.z * (v.z - am.z) * rs.z + b.z;
                o.w = w.w * (v.w - am.w) * rs.w + b.w;
                o.x = ((o.x > 0.f) ? o.x : elu_neg(o.x)) + r.x;
                o.y = ((o.y > 0.f) ? o.y : elu_neg(o.y)) + r.y;
                o.z = ((o.z > 0.f) ? o.z : elu_neg(o.z)) + r.z;
                o.w = ((o.w > 0.f) ? o.w : elu_neg(o.w)) + r.w;
                p.x = pack_bf2(o.x, o.y);
                p.y = pack_bf2(o.z, o.w);
                ((uint2*)(res_out + gr * 64))[q] = p;
            }
            *(uint2*)&atile[row][q * 2] = p;
        }
        __syncthreads();
        if (tile < NTILE) prefetch(tile);     // in flight during MFMA+epilogue
        gemm_phase(atile, Wt, ctile8, rmaxl, H8, hsd, dis, cur, t);
        __syncthreads();
    }
}

// ---------------- per-layer kernels ----------------

#define ACC8(WS, U) \
    acc[0] += WS * ub0(U.x); acc[1] += WS * ub1(U.x); \
    acc[2] += WS * ub2(U.x); acc[3] += WS * ub3(U.x); \
    acc[4] += WS * ub0(U.y); acc[5] += WS * ub1(U.y); \
    acc[6] += WS * ub2(U.y); acc[7] += WS * ub3(U.y);

// pull aggregation: TWO nodes per wave (one per half-wave), 2 quarters x 16 slots
// per node. Self-loop lives in the slot list (prepass), dd multiply hoisted
// post-reduction, single shuffle round (xor 16). Straight-line, 32-bit addressing.
__global__ __launch_bounds__(256, 4) void k_aggregate(const uint8_t* __restrict__ H8,
                                                      const float* __restrict__ hsd,
                                                      const int* __restrict__ psrc,
                                                      const int2* __restrict__ csc,
                                                      const int* __restrict__ rowoff,
                                                      const float* __restrict__ dis,
                                                      const float* __restrict__ bias,
                                                      uint32_t* __restrict__ Out) {
    int wid = threadIdx.x >> 6;
    int lane = threadIdx.x & 63;
    uint32_t hq = (uint32_t)((lane >> 4) & 1);                 // quarter within half-wave
    uint32_t s  = (uint32_t)(lane & 15);
    uint32_t n  = (uint32_t)blockIdx.x * 8u + ((uint32_t)wid << 1) + (uint32_t)(lane >> 5);
    uint32_t s8 = s << 3;                                      // byte offset in row

    // independent loads
    float dd = dis[n];
    int b0 = rowoff[n], b1 = rowoff[n + 1];
    const int4* P = (const int4*)(psrc + ((size_t)n << 5) + (hq << 4));
    int4 pa = P[0], pb = P[1], pc = P[2], pd = P[3];

    // dependent level: 16 weight gathers + 16 row gathers for this quarter's slots
    float h0 = hsd[(uint32_t)pa.x], h1 = hsd[(uint32_t)pa.y];
    float h2 = hsd[(uint32_t)pa.z], h3 = hsd[(uint32_t)pa.w];
    float h4 = hsd[(uint32_t)pb.x], h5 = hsd[(uint32_t)pb.y];
    float h6 = hsd[(uint32_t)pb.z], h7 = hsd[(uint32_t)pb.w];
    uint2 u0 = *(const uint2*)(H8 + (((uint32_t)pa.x << 7) | s8));
    uint2 u1 = *(const uint2*)(H8 + (((uint32_t)pa.y << 7) | s8));
    uint2 u2 = *(const uint2*)(H8 + (((uint32_t)pa.z << 7) | s8));
    uint2 u3 = *(const uint2*)(H8 + (((uint32_t)pa.w << 7) | s8));
    uint2 u4 = *(const uint2*)(H8 + (((uint32_t)pb.x << 7) | s8));
    uint2 u5 = *(const uint2*)(H8 + (((uint32_t)pb.y << 7) | s8));
    uint2 u6 = *(const uint2*)(H8 + (((uint32_t)pb.z << 7) | s8));
    uint2 u7 = *(const uint2*)(H8 + (((uint32_t)pb.w << 7) | s8));

    float acc[8];
#pragma unroll
    for (int k = 0; k < 8; k++) acc[k] = 0.f;

    ACC8(h0, u0); ACC8(h1, u1); ACC8(h2, u2); ACC8(h3, u3);
    ACC8(h4, u4); ACC8(h5, u5); ACC8(h6, u6); ACC8(h7, u7);

    float h8  = hsd[(uint32_t)pc.x], h9  = hsd[(uint32_t)pc.y];
    float h10 = hsd[(uint32_t)pc.z], h11 = hsd[(uint32_t)pc.w];
    float h12 = hsd[(uint32_t)pd.x], h13 = hsd[(uint32_t)pd.y];
    float h14 = hsd[(uint32_t)pd.z], h15 = hsd[(uint32_t)pd.w];
    uint2 u8  = *(const uint2*)(H8 + (((uint32_t)pc.x << 7) | s8));
    uint2 u9  = *(const uint2*)(H8 + (((uint32_t)pc.y << 7) | s8));
    uint2 u10 = *(const uint2*)(H8 + (((uint32_t)pc.z << 7) | s8));
    uint2 u11 = *(const uint2*)(H8 + (((uint32_t)pc.w << 7) | s8));
    uint2 u12 = *(const uint2*)(H8 + (((uint32_t)pd.x << 7) | s8));
    uint2 u13 = *(const uint2*)(H8 + (((uint32_t)pd.y << 7) | s8));
    uint2 u14 = *(const uint2*)(H8 + (((uint32_t)pd.z << 7) | s8));
    uint2 u15 = *(const uint2*)(H8 + (((uint32_t)pd.w << 7) | s8));

    ACC8(h8, u8);  ACC8(h9, u9);  ACC8(h10, u10); ACC8(h11, u11);
    ACC8(h12, u12); ACC8(h13, u13); ACC8(h14, u14); ACC8(h15, u15);

    float offs = ((h0 + h1) + (h2 + h3)) + ((h4 + h5) + (h6 + h7))
               + ((h8 + h9) + (h10 + h11)) + ((h12 + h13) + (h14 + h15));

    // rare: deg >= 32 -> self didn't fit in slots; add self + overflow edges
    if (b1 - b0 >= NSLOT) {
        float wsf = (hq == 0) ? hsd[n] : 0.f;      // self counted once per node
        uint2 uu = *(const uint2*)(H8 + ((n << 7) | s8));
        ACC8(wsf, uu);
        offs += wsf;
        for (int j = b0 + NSLOT + (int)hq; j < b1; j += 2) {
            uint32_t sx = (uint32_t)csc[j].x;
            float w = hsd[sx];
            uint2 u = *(const uint2*)(H8 + ((sx << 7) | s8));
            ACC8(w, u);
            offs += w;
        }
    }

    // reduce across the two quarters of this half-wave
#pragma unroll
    for (int k = 0; k < 8; k++) acc[k] += __shfl_xor(acc[k], 16);
    offs += __shfl_xor(offs, 16);

    float corr = -128.f * offs;
    // lane (hq,s): writes features s*8 + hq*4 .. +3 as 2 packed bf16 uints
    float a0 = hq ? acc[4] : acc[0];
    float a1 = hq ? acc[5] : acc[1];
    float a2 = hq ? acc[6] : acc[2];
    float a3 = hq ? acc[7] : acc[3];
    float4 bb = ((const float4*)bias)[(s << 1) | hq];
    uint2 ov;
    ov.x = pack_bf2(fmaf(dd, a0 + corr, bb.x), fmaf(dd, a1 + corr, bb.y));
    ov.y = pack_bf2(fmaf(dd, a2 + corr, bb.z), fmaf(dd, a3 + corr, bb.w));
    *(uint2*)(Out + ((n << 6) | (s << 2) | (hq << 1))) = ov;
}

// GraphNorm stats from bf16 agg: one block per graph, 512 thr (8 parts x 64 uints)
__global__ __launch_bounds__(512) void k_stats(const uint32_t* __restrict__ A, const int* __restrict__ gstart,
                                               const float* __restrict__ mscale,
                                               float* __restrict__ amean, float* __restrict__ rstd) {
    __shared__ float L1[8][DIM];
    __shared__ float L2[8][DIM];
    int g = blockIdx.x;
    int t = threadIdx.x;
    int f2 = t & 63;
    int p = t >> 6;
    int s0 = gstart[g], s1 = gstart[g + 1];
    float sa = 0.f, sb = 0.f, qa = 0.f, qb = 0.f;
    for (int n = s0 + p; n < s1; n += 8) {
        uint32_t u = A[(size_t)n * 64 + f2];
        float a = bf_lo(u), b = bf_hi(u);
        sa += a; qa += a * a;
        sb += b; qb += b * b;
    }
    L1[p][2 * f2] = sa; L1[p][2 * f2 + 1] = sb;
    L2[p][2 * f2] = qa; L2[p][2 * f2 + 1] = qb;
    __syncthreads();
    if (t < DIM) {
        float s = 0.f, s2 = 0.f;
#pragma unroll
        for (int i = 0; i < 8; i++) { s += L1[i][t]; s2 += L2[i][t]; }
        int cnt = s1 - s0;
        float inv = (cnt > 0) ? 1.0f / (float)cnt : 0.f;
        float m = s * inv;
        float a = mscale[t];
        float var = s2 * inv - (2.f * a - a * a) * m * m;
        amean[g * DIM + t] = a * m;
        rstd[g * DIM + t] = rsqrtf(var + EPSV);
    }
}

// final-layer norm+ELU+residual + x write + partial pool sums (8 blocks/graph).
__global__ __launch_bounds__(512) void k_norm_pool(const uint32_t* __restrict__ A,
                                                   const uint32_t* __restrict__ resb,
                                                   const int* __restrict__ gstart,
                                                   const float* __restrict__ amean, const float* __restrict__ rstd,
                                                   const float* __restrict__ gw, const float* __restrict__ gb,
                                                   float* __restrict__ outx, float* __restrict__ pooled) {
    __shared__ float L[8][DIM];
    int g = blockIdx.x >> 3;
    int part = blockIdx.x & 7;
    int t = threadIdx.x;
    int f2 = t & 63;
    int p = t >> 6;
    int slice = part * 8 + p;                 // 0..63
    int s0 = gstart[g], s1 = gstart[g + 1];
    float am0 = amean[g * DIM + 2 * f2], am1 = amean[g * DIM + 2 * f2 + 1];
    float rs0 = rstd[g * DIM + 2 * f2],  rs1 = rstd[g * DIM + 2 * f2 + 1];
    float w0_ = gw[2 * f2], w1_ = gw[2 * f2 + 1];
    float b0_ = gb[2 * f2], b1_ = gb[2 * f2 + 1];
    float p0 = 0.f, p1 = 0.f;
    for (int n = s0 + slice; n < s1; n += 64) {
        uint32_t u = A[(size_t)n * 64 + f2];
        uint32_t ur = resb[(size_t)n * 64 + f2];
        float a = bf_lo(u), b = bf_hi(u);
        float r0 = bf_lo(ur), r1 = bf_hi(ur);
        float o0 = w0_ * (a - am0) * rs0 + b0_;
        float o1 = w1_ * (b - am1) * rs1 + b1_;
        o0 = ((o0 > 0.f) ? o0 : elu_neg(o0)) + r0;
        o1 = ((o1 > 0.f) ? o1 : elu_neg(o1)) + r1;
        ((float2*)(outx + (size_t)n * DIM))[f2] = make_float2(o0, o1);
        p0 += o0; p1 += o1;
    }
    L[p][2 * f2] = p0; L[p][2 * f2 + 1] = p1;
    __syncthreads();
    if (t < DIM) {
        float s = 0.f;
#pragma unroll
        for (int i = 0; i < 8; i++) s += L[i][t];
        if (s != 0.f) atomicAdd(&pooled[g * DIM + t], s);
    }
}

// dense head from pooled sums: 128 blocks x 128 threads (tiny)
__global__ __launch_bounds__(128) void k_head(const float* __restrict__ pooled,
                                              const float* __restrict__ w1, const float* __restrict__ b1,
                                              const float* __restrict__ gamma, const float* __restrict__ beta,
                                              const float* __restrict__ rmean, const float* __restrict__ rvar,
                                              const float* __restrict__ w2, const float* __restrict__ b2,
                                              float* __restrict__ zout) {
    __shared__ float sz[DIM];
    int g = blockIdx.x, t = threadIdx.x;
    const float* sp = pooled + g * DIM;
    float acc = b1[t];
#pragma unroll 8
    for (int k = 0; k < DIM; k++) acc += sp[k] * w1[k * DIM + t];
    acc = gamma[t] * (acc - rmean[t]) * rsqrtf(rvar[t] + EPSV) + beta[t];
    sz[t] = fmaxf(acc, 0.f);
    __syncthreads();
    if (t < NCLS) {
        float a2 = b2[t];
#pragma unroll 8
        for (int k = 0; k < DIM; k++) a2 += sz[k] * w2[k * NCLS + t];
        zout[g * NCLS + t] = a2;
    }
}

// ---------------- launch ----------------

extern "C" void kernel_launch(void* const* d_in, const int* in_sizes, int n_in,
                              void* d_out, int out_size, void* d_ws, size_t ws_size,
                              hipStream_t stream) {
    const float* x_in   = (const float*)d_in[0];
    const int*   ei     = (const int*)d_in[1];
    const int*   batch  = (const int*)d_in[2];
    const float* conv_w = (const float*)d_in[3];
    const float* conv_b = (const float*)d_in[4];
    const float* gn_w   = (const float*)d_in[5];
    const float* gn_b   = (const float*)d_in[6];
    const float* gn_ms  = (const float*)d_in[7];
    const float* w1     = (const float*)d_in[8];
    const float* b1     = (const float*)d_in[9];
    const float* bng    = (const float*)d_in[10];
    const float* bnb    = (const float*)d_in[11];
    const float* bnm    = (const float*)d_in[12];
    const float* bnv    = (const float*)d_in[13];
    const float* w2     = (const float*)d_in[14];
    const float* b2     = (const float*)d_in[15];

    float* out_x = (float*)d_out;
    float* out_z = out_x + (size_t)N_NODES * DIM;

    char* ws = (char*)d_ws;
    size_t off = 0;
    auto alloc = [&](size_t bytes) -> void* {
        void* p = ws + off;
        off += (bytes + 255) / 256 * 256;
        return p;
    };
    uint8_t* h8      = (uint8_t*)alloc(sizeof(uint8_t) * (size_t)N_PAD * 128);    // int8 H (padded)
    float*   hsd     = (float*)alloc(sizeof(float) * (size_t)N_PAD);              // per-row scale*dis
    uint32_t* agg    = (uint32_t*)alloc(sizeof(uint32_t) * (size_t)N_NODES * 64); // bf16 agg
    uint32_t* resb   = (uint32_t*)alloc(sizeof(uint32_t) * (size_t)N_NODES * 64); // bf16 residual stream
    int2*  csc       = (int2*)alloc(sizeof(int2) * (size_t)N_EDGES);              // merged (src, w) — overflow only
    int2*  binned    = (int2*)alloc(sizeof(int2) * (size_t)N_EDGES);              // pass-1 bins (src, dst)
    int*   psrc      = (int*)alloc(sizeof(int) * (size_t)N_NODES * NSLOT);        // fixed 32-slot padded srcs
    uint32_t* wt     = (uint32_t*)alloc(sizeof(uint32_t) * NLAYERS * DIM * 64);   // bf16 W^T
    float* dis       = (float*)alloc(sizeof(float) * N_NODES);
    int*   rowoff    = (int*)alloc(sizeof(int) * (N_NODES + 1));
    int*   bcnt      = (int*)alloc(sizeof(int) * NBUCKET);
    int*   boffb     = (int*)alloc(sizeof(int) * (NBUCKET + 1));
    int*   bcur      = (int*)alloc(sizeof(int) * NBUCKET);
    int*   gstart    = (int*)alloc(sizeof(int) * (NGRAPH + 1));
    float* amean     = (float*)alloc(sizeof(float) * NGRAPH * DIM);
    float* rstd      = (float*)alloc(sizeof(float) * NGRAPH * DIM);
    float* pooled    = (float*)alloc(sizeof(float) * NGRAPH * DIM);

    // ---- prepass ----
    k_node_meta<<<(N_NODES + 255) / 256, 256, 0, stream>>>(batch, gstart, bcnt, pooled);
    k_bhist<<<P1_BLOCKS, 256, 0, stream>>>(ei, bcnt);
    k_bscan<<<1, 256, 0, stream>>>(bcnt, boffb, bcur);
    k_bin_edges<<<P1_BLOCKS, 256, 0, stream>>>(ei, bcur, binned);
    k_bucket_build<<<NBUCKET, 256, 0, stream>>>(binned, boffb, rowoff, dis, psrc);
    k_scatter<<<NBUCKET, 256, 0, stream>>>(binned, dis, rowoff, boffb, csc, psrc);
    k_cast_w<<<(NLAYERS * DIM * 64 + 255) / 256, 256, 0, stream>>>(conv_w, wt);

    // ---- layers ----
    k_gemm0<<<GEMM_GRID, 256, 0, stream>>>(x_in, wt, h8, hsd, dis);
    for (int l = 0; l < NLAYERS; l++) {
        k_aggregate<<<N_NODES / 8, 256, 0, stream>>>(h8, hsd, psrc, csc, rowoff, dis,
                                                     conv_b + (size_t)l * DIM, agg);
        k_stats<<<NGRAPH, 512, 0, stream>>>(agg, gstart, gn_ms + (size_t)l * DIM, amean, rstd);
        if (l == 0) {
            k_norm_gemm<false><<<GEMM_GRID, 256, 0, stream>>>(agg, batch, amean, rstd, gn_w, gn_b,
                                                              (const void*)x_in, resb,
                                                              wt + (size_t)1 * DIM * 64, h8, hsd, dis);
        } else if (l < NLAYERS - 1) {
            k_norm_gemm<true><<<GEMM_GRID, 256, 0, stream>>>(agg, batch, amean, rstd,
                                                             gn_w + (size_t)l * DIM, gn_b + (size_t)l * DIM,
                                                             (const void*)resb, resb,
                                                             wt + (size_t)(l + 1) * DIM * 64, h8, hsd, dis);
        } else {
            k_norm_pool<<<NGRAPH * POOL_PARTS, 512, 0, stream>>>(agg, resb, gstart, amean, rstd,
                                                                 gn_w + (size_t)l * DIM, gn_b + (size_t)l * DIM,
                                                                 out_x, pooled);
            k_head<<<NGRAPH, 128, 0, stream>>>(pooled, w1, b1, bng, bnb, bnm, bnv, w2, b2, out_z);
        }
    }
}

// Round 10
// 643.948 us; speedup vs baseline: 1.2549x; 1.2549x over previous
//
#include <hip/hip_runtime.h>
#include <stdint.h>

#define N_NODES 100000
#define N_PAD   100032            // 1563 * 64, padded rows for MFMA GEMM
#define N_EDGES 1600000
#define DIM 128
#define NLAYERS 4
#define NGRAPH 128
#define NCLS 10
#define EPSV 1e-5f
#define NSLOT 32                  // fixed padded slots per node (P(deg>32) ~ 3e-5)
#define POOL_PARTS 8              // blocks per graph in split per-graph kernels

#define BIN_SHIFT 9
#define NBUCKET ((N_NODES + 511) >> 9)              // 196
#define P1_EPB 4096
#define P1_BLOCKS ((N_EDGES + P1_EPB - 1) / P1_EPB) // 391

typedef __attribute__((ext_vector_type(8))) short short8_t;   // 8 bf16
typedef __attribute__((ext_vector_type(4))) float float4_t;   // 4 fp32 acc

// ---------------- bf16 / int8 helpers ----------------

__device__ __forceinline__ float bf_lo(uint32_t u) { return __uint_as_float(u << 16); }
__device__ __forceinline__ float bf_hi(uint32_t u) { return __uint_as_float(u & 0xffff0000u); }
__device__ __forceinline__ uint32_t f2bf_rne(float f) {
    uint32_t x = __float_as_uint(f);
    return (x + 0x7fffu + ((x >> 16) & 1u)) >> 16;
}
__device__ __forceinline__ uint32_t pack_bf2(float a, float b) {
    return f2bf_rne(a) | (f2bf_rne(b) << 16);
}
__device__ __forceinline__ float4 unpack4(uint2 u) {
    return make_float4(bf_lo(u.x), bf_hi(u.x), bf_lo(u.y), bf_hi(u.y));
}
// these compile to v_cvt_f32_ubyte{0..3} (single VALU op each)
__device__ __forceinline__ float ub0(uint32_t u) { return (float)( u        & 0xffu); }
__device__ __forceinline__ float ub1(uint32_t u) { return (float)((u >>  8) & 0xffu); }
__device__ __forceinline__ float ub2(uint32_t u) { return (float)((u >> 16) & 0xffu); }
__device__ __forceinline__ float ub3(uint32_t u) { return (float)( u >> 24        ); }
// fast ELU negative branch: exp(x)-1 via v_exp_f32 (tolerance-safe vs expm1f)
__device__ __forceinline__ float elu_neg(float x) { return __expf(x) - 1.f; }

// ---------------- prepass kernels ----------------

// graph boundaries from SORTED batch (no atomics); zero bucket counters,
// pooled accumulator, and per-graph stats accumulators
__global__ void k_node_meta(const int* __restrict__ batch, int* __restrict__ gstart,
                            int* __restrict__ bcnt, float* __restrict__ pooled,
                            float* __restrict__ gsum, float* __restrict__ gsqs) {
    int i = blockIdx.x * blockDim.x + threadIdx.x;
    if (i < NBUCKET) bcnt[i] = 0;
    if (i < NGRAPH * DIM) { pooled[i] = 0.f; gsum[i] = 0.f; gsqs[i] = 0.f; }
    if (i >= N_NODES) return;
    int b = batch[i];
    if (i == 0) {
        for (int g = 0; g <= b; g++) gstart[g] = 0;
    } else {
        int bp = batch[i - 1];
        for (int g = bp + 1; g <= b; g++) gstart[g] = i;
    }
    if (i == N_NODES - 1) {
        for (int g = b + 1; g <= NGRAPH; g++) gstart[g] = N_NODES;
    }
}

// histogram edges by dst bucket
__global__ __launch_bounds__(256) void k_bhist(const int* __restrict__ ei, int* __restrict__ bcnt) {
    __shared__ int hist[NBUCKET];
    int t = threadIdx.x;
    for (int i = t; i < NBUCKET; i += 256) hist[i] = 0;
    __syncthreads();
    int e0 = blockIdx.x * P1_EPB;
    int e1 = e0 + P1_EPB; if (e1 > N_EDGES) e1 = N_EDGES;
    for (int e = e0 + t; e < e1; e += 256) atomicAdd(&hist[ei[N_EDGES + e] >> BIN_SHIFT], 1);
    __syncthreads();
    for (int i = t; i < NBUCKET; i += 256) if (hist[i]) atomicAdd(&bcnt[i], hist[i]);
}

// exclusive scan of bucket counts -> bucket_off[0..NBUCKET]; init bcur
__global__ __launch_bounds__(256) void k_bscan(const int* __restrict__ bcnt,
                                               int* __restrict__ bucket_off, int* __restrict__ bcur) {
    __shared__ int s[256];
    int t = threadIdx.x;
    int v = (t < NBUCKET) ? bcnt[t] : 0;
    s[t] = v; __syncthreads();
    for (int off = 1; off < 256; off <<= 1) {
        int a = (t >= off) ? s[t - off] : 0;
        __syncthreads();
        s[t] += a;
        __syncthreads();
    }
    if (t < NBUCKET) { bucket_off[t] = s[t] - v; bcur[t] = s[t] - v; }
    if (t == 0) bucket_off[NBUCKET] = s[255];
}

// pass 1: bin edges by dst bucket (append-sequential writes per bucket)
__global__ __launch_bounds__(256) void k_bin_edges(const int* __restrict__ ei,
                                                   int* __restrict__ bcur,
                                                   int2* __restrict__ binned) {
    __shared__ int hist[NBUCKET];
    __shared__ int base[NBUCKET];
    int t = threadIdx.x;
    int e0 = blockIdx.x * P1_EPB;
    int e1 = e0 + P1_EPB; if (e1 > N_EDGES) e1 = N_EDGES;
    for (int i = t; i < NBUCKET; i += 256) hist[i] = 0;
    __syncthreads();
    int myrank[P1_EPB / 256];
    int cnt = 0;
    for (int e = e0 + t; e < e1; e += 256) {
        int d = ei[N_EDGES + e];
        myrank[cnt++] = atomicAdd(&hist[d >> BIN_SHIFT], 1);
    }
    __syncthreads();
    for (int i = t; i < NBUCKET; i += 256) base[i] = atomicAdd(&bcur[i], hist[i]);
    __syncthreads();
    cnt = 0;
    for (int e = e0 + t; e < e1; e += 256) {
        int s = ei[e];
        int d = ei[N_EDGES + e];
        binned[base[d >> BIN_SHIFT] + myrank[cnt++]] = make_int2(s, d);
    }
}

// per-bucket: histogram dst -> local scan -> rowoff + dis; sentinel-pad psrc slots.
// FIRST pad slot of each node with deg < NSLOT is the node ITSELF: its weight
// dd*hsd[n] = dis^2 * qscale is exactly the GCN self-loop term.
__global__ __launch_bounds__(256) void k_bucket_build(const int2* __restrict__ binned,
                                                      const int* __restrict__ bucket_off,
                                                      int* __restrict__ rowoff,
                                                      float* __restrict__ dis,
                                                      int* __restrict__ psrc) {
    __shared__ int cnt[512];
    __shared__ int sa[512];
    __shared__ int sb[512];
    int b = blockIdx.x;
    int t = threadIdx.x;
    int n0 = b << BIN_SHIFT;
    int j0 = bucket_off[b], j1 = bucket_off[b + 1];
    cnt[t] = 0; cnt[t + 256] = 0;
    __syncthreads();
    for (int j = j0 + t; j < j1; j += 256) atomicAdd(&cnt[binned[j].y & 511], 1);
    __syncthreads();
    sa[t] = cnt[t]; sa[t + 256] = cnt[t + 256];
    __syncthreads();
    int* A = sa; int* B = sb;
    for (int off = 1; off < 512; off <<= 1) {
        int i0 = t, i1 = t + 256;
        B[i0] = A[i0] + ((i0 >= off) ? A[i0 - off] : 0);
        B[i1] = A[i1] + ((i1 >= off) ? A[i1 - off] : 0);
        __syncthreads();
        int* tmp = A; A = B; B = tmp;
    }
    // A = inclusive scan
    for (int i = t; i < 512; i += 256) {
        int n = n0 + i;
        if (n < N_NODES) {
            rowoff[n] = j0 + A[i] - cnt[i];
            dis[n] = rsqrtf((float)(1 + cnt[i]));
        }
    }
    if (b == NBUCKET - 1 && t == 0) rowoff[N_NODES] = N_EDGES;
    // pad slots: slot cnt = SELF; slots > cnt = sentinel (hsd[N_NODES] == 0)
    for (int idx = t; idx < 512 * NSLOT; idx += 256) {
        int i = idx >> 5, k = idx & (NSLOT - 1);
        int n = n0 + i;
        if (n < N_NODES && k >= cnt[i]) psrc[(size_t)n * NSLOT + k] = (k == cnt[i]) ? n : N_NODES;
    }
}

// pass 2: one block per bucket; scatter within the bucket's L2-resident window.
// writes full csc (for rare deg>=32 overflow) and first-32 padded psrc slots.
__global__ __launch_bounds__(256) void k_scatter(const int2* __restrict__ binned,
                                                 const float* __restrict__ dis,
                                                 const int* __restrict__ rowoff,
                                                 const int* __restrict__ bucket_off,
                                                 int2* __restrict__ csc,
                                                 int* __restrict__ psrc) {
    __shared__ int lcur[512];
    int b = blockIdx.x;
    int t = threadIdx.x;
    lcur[t] = 0; lcur[t + 256] = 0;
    __syncthreads();
    int j0 = bucket_off[b], j1 = bucket_off[b + 1];
    for (int j = j0 + t; j < j1; j += 256) {
        int2 sd = binned[j];
        float w = dis[sd.x] * dis[sd.y];
        int rank = atomicAdd(&lcur[sd.y & 511], 1);
        csc[rowoff[sd.y] + rank] = make_int2(sd.x, __float_as_int(w));
        if (rank < NSLOT) psrc[(size_t)sd.y * NSLOT + rank] = sd.x;
    }
}

// cast conv_w (fp32, [L][K][N]) -> Wt (bf16, [L][N][K] packed as uint pairs along K)
__global__ void k_cast_w(const float* __restrict__ W, uint32_t* __restrict__ Wt) {
    int i = blockIdx.x * blockDim.x + threadIdx.x;    // over L*128*64
    if (i >= NLAYERS * DIM * 64) return;
    int l = i / (DIM * 64);
    int n = (i / 64) % DIM;
    int ku = i % 64;
    const float* Wl = W + (size_t)l * DIM * DIM;
    float w0 = Wl[(2 * ku) * DIM + n];
    float w1 = Wl[(2 * ku + 1) * DIM + n];
    Wt[i] = pack_bf2(w0, w1);
}

// ---------------- GEMM cores ----------------

// MFMA phase: A-tile in LDS (uint [64][68], bf16 pairs), B = Wt global.
// Per-row amax computed IN-REGISTER from MFMA accumulators, quantized
// in-register, int8 bytes bounced through a small LDS tile for coalesced stores.
__device__ __forceinline__ void gemm_phase(const uint32_t (*atile)[68], const uint32_t* __restrict__ Wt,
                                           uint8_t (*ctile8)[132], float* rmaxl,
                                           uint8_t* __restrict__ H8,
                                           float* __restrict__ hsd, const float* __restrict__ dis,
                                           int blk, int t) {
    int wid = t >> 6;
    int lane = t & 63;
    int quad = lane >> 4;
    int s15 = lane & 15;

    float4_t acc[8];
#pragma unroll
    for (int i = 0; i < 8; i++) acc[i] = (float4_t){0.f, 0.f, 0.f, 0.f};

#pragma unroll
    for (int kk = 0; kk < 4; kk++) {
        uint4 au = *(const uint4*)&atile[wid * 16 + s15][quad * 4 + kk * 16];
        short8_t a = __builtin_bit_cast(short8_t, au);
#pragma unroll
        for (int nt = 0; nt < 8; nt++) {
            uint4 bu = *(const uint4*)(Wt + (size_t)(nt * 16 + s15) * 64 + kk * 16 + quad * 4);
            short8_t b = __builtin_bit_cast(short8_t, bu);
            acc[nt] = __builtin_amdgcn_mfma_f32_16x16x32_bf16(a, b, acc[nt], 0, 0, 0);
        }
    }
    __syncthreads();       // A-tile dead; reuse LDS for int8 C + rmax

    // per-row amax: rows of this quad are wid*16+quad*4+r; reduce over 16 s15 lanes
    float sinv[4];
#pragma unroll
    for (int r = 0; r < 4; r++) {
        float m = fabsf(acc[0][r]);
#pragma unroll
        for (int nt = 1; nt < 8; nt++) m = fmaxf(m, fabsf(acc[nt][r]));
        m = fmaxf(m, __shfl_xor(m, 1));
        m = fmaxf(m, __shfl_xor(m, 2));
        m = fmaxf(m, __shfl_xor(m, 4));
        m = fmaxf(m, __shfl_xor(m, 8));
        if (s15 == 0) rmaxl[wid * 16 + quad * 4 + r] = m;
        sinv[r] = (m > 0.f) ? 127.f / m : 0.f;
    }
    // quantize in-register, write bytes to LDS
#pragma unroll
    for (int nt = 0; nt < 8; nt++) {
#pragma unroll
        for (int r = 0; r < 4; r++) {
            int qv = (int)fmaf(acc[nt][r], sinv[r], 128.5f);   // in [1,255]
            ctile8[wid * 16 + quad * 4 + r][nt * 16 + s15] = (uint8_t)qv;
        }
    }
    __syncthreads();
    uint8_t* Hb = H8 + (size_t)blk * 64 * 128;
    float* Hsb = hsd + (size_t)blk * 64;
#pragma unroll
    for (int i = 0; i < 8; i++) {
        int idx = t + 256 * i;            // 2048 uints (64 rows x 32)
        int row = idx >> 5, cu = idx & 31;
        uint32_t v = *(const uint32_t*)&ctile8[row][cu * 4];
        ((uint32_t*)Hb)[(size_t)row * 32 + cu] = v;
        if (cu == 0) {
            size_t gr = (size_t)blk * 64 + row;
            float dv = (gr < N_NODES) ? dis[gr] : 0.f;   // pad rows -> 0 weight
            Hsb[row] = rmaxl[row] * (1.f / 127.f) * dv;
        }
    }
}

#define GEMM_SMEM \
    __shared__ __align__(16) char smem[64 * 68 * 4]; \
    uint32_t (*atile)[68] = (uint32_t(*)[68])smem; \
    uint8_t (*ctile8)[132] = (uint8_t(*)[132])smem; \
    float* rmaxl = (float*)(smem + 64 * 132);

// layer-0 GEMM: cast x_in (fp32) to bf16 A-tile in LDS, then MFMA
__global__ __launch_bounds__(256) void k_gemm0(const float* __restrict__ X, const uint32_t* __restrict__ Wt,
                                               uint8_t* __restrict__ H8, float* __restrict__ hsd,
                                               const float* __restrict__ dis) {
    GEMM_SMEM
    int t = threadIdx.x;
    size_t row0 = (size_t)blockIdx.x * 64;
#pragma unroll
    for (int i = 0; i < 8; i++) {
        int idx = t + 256 * i;            // 2048 float4-groups
        int row = idx >> 5, q = idx & 31;
        size_t gr = row0 + row;
        uint2 p = make_uint2(0u, 0u);
        if (gr < N_NODES) {
            float4 v = ((const float4*)(X + gr * DIM))[q];
            p.x = pack_bf2(v.x, v.y);
            p.y = pack_bf2(v.z, v.w);
        }
        *(uint2*)&atile[row][q * 2] = p;
    }
    __syncthreads();
    gemm_phase(atile, Wt, ctile8, rmaxl, H8, hsd, dis, blockIdx.x, t);
}

// fused GraphNorm+ELU+residual (layer l) + GEMM (layer l+1).
// A = agg in bf16; residual in fp32 (layer 0) or bf16 (layers 1,2); writes bf16 residual out.
template <bool RBF>
__global__ __launch_bounds__(256) void k_norm_gemm(const uint32_t* __restrict__ A, const int* __restrict__ batch,
                                                   const float* __restrict__ amean, const float* __restrict__ rstd,
                                                   const float* __restrict__ gw, const float* __restrict__ gb,
                                                   const void* __restrict__ res, uint32_t* __restrict__ res_out,
                                                   const uint32_t* __restrict__ Wt,
                                                   uint8_t* __restrict__ H8, float* __restrict__ hsd,
                                                   const float* __restrict__ dis) {
    GEMM_SMEM
    int t = threadIdx.x;
    size_t row0 = (size_t)blockIdx.x * 64;
#pragma unroll
    for (int i = 0; i < 8; i++) {
        int idx = t + 256 * i;            // 2048 float4-groups
        int row = idx >> 5, q = idx & 31;
        size_t gr = row0 + row;
        uint2 p = make_uint2(0u, 0u);
        if (gr < N_NODES) {
            int g = batch[gr];
            float4 v = unpack4(((const uint2*)(A + gr * 64))[q]);
            float4 am = ((const float4*)amean)[g * 32 + q];
            float4 rs = ((const float4*)rstd)[g * 32 + q];
            float4 w = ((const float4*)gw)[q];
            float4 b = ((const float4*)gb)[q];
            float4 r;
            if (RBF) r = unpack4(((const uint2*)((const uint32_t*)res + gr * 64))[q]);
            else     r = ((const float4*)res)[gr * 32 + q];
            float4 o;
            o.x = w.x * (v.x - am.x) * rs.x + b.x;
            o.y = w.y * (v.y - am.y) * rs.y + b.y;
            o.z = w.z * (v.z - am.z) * rs.z + b.z;
            o.w = w.w * (v.w - am.w) * rs.w + b.w;
            o.x = ((o.x > 0.f) ? o.x : elu_neg(o.x)) + r.x;
            o.y = ((o.y > 0.f) ? o.y : elu_neg(o.y)) + r.y;
            o.z = ((o.z > 0.f) ? o.z : elu_neg(o.z)) + r.z;
            o.w = ((o.w > 0.f) ? o.w : elu_neg(o.w)) + r.w;
            p.x = pack_bf2(o.x, o.y);
            p.y = pack_bf2(o.z, o.w);
            ((uint2*)(res_out + gr * 64))[q] = p;
        }
        *(uint2*)&atile[row][q * 2] = p;
    }
    __syncthreads();
    gemm_phase(atile, Wt, ctile8, rmaxl, H8, hsd, dis, blockIdx.x, t);
}

// ---------------- per-layer kernels ----------------

#define ACC8(WS, U) \
    acc[0] += WS * ub0(U.x); acc[1] += WS * ub1(U.x); \
    acc[2] += WS * ub2(U.x); acc[3] += WS * ub3(U.x); \
    acc[4] += WS * ub0(U.y); acc[5] += WS * ub1(U.y); \
    acc[6] += WS * ub2(U.y); acc[7] += WS * ub3(U.y);

// pull aggregation: TWO nodes per wave (one per half-wave), 2 quarters x 16 slots
// per node. Self-loop lives in the slot list (prepass), dd multiply hoisted
// post-reduction, single shuffle round (xor 16). Straight-line, 32-bit addressing.
__global__ __launch_bounds__(256, 4) void k_aggregate(const uint8_t* __restrict__ H8,
                                                      const float* __restrict__ hsd,
                                                      const int* __restrict__ psrc,
                                                      const int2* __restrict__ csc,
                                                      const int* __restrict__ rowoff,
                                                      const float* __restrict__ dis,
                                                      const float* __restrict__ bias,
                                                      uint32_t* __restrict__ Out) {
    int wid = threadIdx.x >> 6;
    int lane = threadIdx.x & 63;
    uint32_t hq = (uint32_t)((lane >> 4) & 1);                 // quarter within half-wave
    uint32_t s  = (uint32_t)(lane & 15);
    uint32_t n  = (uint32_t)blockIdx.x * 8u + ((uint32_t)wid << 1) + (uint32_t)(lane >> 5);
    uint32_t s8 = s << 3;                                      // byte offset in row

    // independent loads
    float dd = dis[n];
    int b0 = rowoff[n], b1 = rowoff[n + 1];
    const int4* P = (const int4*)(psrc + ((size_t)n << 5) + (hq << 4));
    int4 pa = P[0], pb = P[1], pc = P[2], pd = P[3];

    // dependent level: 16 weight gathers + 16 row gathers for this quarter's slots
    float h0 = hsd[(uint32_t)pa.x], h1 = hsd[(uint32_t)pa.y];
    float h2 = hsd[(uint32_t)pa.z], h3 = hsd[(uint32_t)pa.w];
    float h4 = hsd[(uint32_t)pb.x], h5 = hsd[(uint32_t)pb.y];
    float h6 = hsd[(uint32_t)pb.z], h7 = hsd[(uint32_t)pb.w];
    uint2 u0 = *(const uint2*)(H8 + (((uint32_t)pa.x << 7) | s8));
    uint2 u1 = *(const uint2*)(H8 + (((uint32_t)pa.y << 7) | s8));
    uint2 u2 = *(const uint2*)(H8 + (((uint32_t)pa.z << 7) | s8));
    uint2 u3 = *(const uint2*)(H8 + (((uint32_t)pa.w << 7) | s8));
    uint2 u4 = *(const uint2*)(H8 + (((uint32_t)pb.x << 7) | s8));
    uint2 u5 = *(const uint2*)(H8 + (((uint32_t)pb.y << 7) | s8));
    uint2 u6 = *(const uint2*)(H8 + (((uint32_t)pb.z << 7) | s8));
    uint2 u7 = *(const uint2*)(H8 + (((uint32_t)pb.w << 7) | s8));

    float acc[8];
#pragma unroll
    for (int k = 0; k < 8; k++) acc[k] = 0.f;

    ACC8(h0, u0); ACC8(h1, u1); ACC8(h2, u2); ACC8(h3, u3);
    ACC8(h4, u4); ACC8(h5, u5); ACC8(h6, u6); ACC8(h7, u7);

    float h8  = hsd[(uint32_t)pc.x], h9  = hsd[(uint32_t)pc.y];
    float h10 = hsd[(uint32_t)pc.z], h11 = hsd[(uint32_t)pc.w];
    float h12 = hsd[(uint32_t)pd.x], h13 = hsd[(uint32_t)pd.y];
    float h14 = hsd[(uint32_t)pd.z], h15 = hsd[(uint32_t)pd.w];
    uint2 u8  = *(const uint2*)(H8 + (((uint32_t)pc.x << 7) | s8));
    uint2 u9  = *(const uint2*)(H8 + (((uint32_t)pc.y << 7) | s8));
    uint2 u10 = *(const uint2*)(H8 + (((uint32_t)pc.z << 7) | s8));
    uint2 u11 = *(const uint2*)(H8 + (((uint32_t)pc.w << 7) | s8));
    uint2 u12 = *(const uint2*)(H8 + (((uint32_t)pd.x << 7) | s8));
    uint2 u13 = *(const uint2*)(H8 + (((uint32_t)pd.y << 7) | s8));
    uint2 u14 = *(const uint2*)(H8 + (((uint32_t)pd.z << 7) | s8));
    uint2 u15 = *(const uint2*)(H8 + (((uint32_t)pd.w << 7) | s8));

    ACC8(h8, u8);  ACC8(h9, u9);  ACC8(h10, u10); ACC8(h11, u11);
    ACC8(h12, u12); ACC8(h13, u13); ACC8(h14, u14); ACC8(h15, u15);

    float offs = ((h0 + h1) + (h2 + h3)) + ((h4 + h5) + (h6 + h7))
               + ((h8 + h9) + (h10 + h11)) + ((h12 + h13) + (h14 + h15));

    // rare: deg >= 32 -> self didn't fit in slots; add self + overflow edges
    if (b1 - b0 >= NSLOT) {
        float wsf = (hq == 0) ? hsd[n] : 0.f;      // self counted once per node
        uint2 uu = *(const uint2*)(H8 + ((n << 7) | s8));
        ACC8(wsf, uu);
        offs += wsf;
        for (int j = b0 + NSLOT + (int)hq; j < b1; j += 2) {
            uint32_t sx = (uint32_t)csc[j].x;
            float w = hsd[sx];
            uint2 u = *(const uint2*)(H8 + ((sx << 7) | s8));
            ACC8(w, u);
            offs += w;
        }
    }

    // reduce across the two quarters of this half-wave
#pragma unroll
    for (int k = 0; k < 8; k++) acc[k] += __shfl_xor(acc[k], 16);
    offs += __shfl_xor(offs, 16);

    float corr = -128.f * offs;
    // lane (hq,s): writes features s*8 + hq*4 .. +3 as 2 packed bf16 uints
    float a0 = hq ? acc[4] : acc[0];
    float a1 = hq ? acc[5] : acc[1];
    float a2 = hq ? acc[6] : acc[2];
    float a3 = hq ? acc[7] : acc[3];
    float4 bb = ((const float4*)bias)[(s << 1) | hq];
    uint2 ov;
    ov.x = pack_bf2(fmaf(dd, a0 + corr, bb.x), fmaf(dd, a1 + corr, bb.y));
    ov.y = pack_bf2(fmaf(dd, a2 + corr, bb.z), fmaf(dd, a3 + corr, bb.w));
    *(uint2*)(Out + ((n << 6) | (s << 2) | (hq << 1))) = ov;
}

// GraphNorm stats, split: 8 blocks per graph accumulate partial sum/sumsq
// into global fp32 accumulators (parallelism fix: 1024 blocks vs 128).
__global__ __launch_bounds__(512) void k_stats_part(const uint32_t* __restrict__ A,
                                                    const int* __restrict__ gstart,
                                                    float* __restrict__ gsum, float* __restrict__ gsqs) {
    __shared__ float L1[8][DIM];
    __shared__ float L2[8][DIM];
    int g = blockIdx.x >> 3;
    int part = blockIdx.x & 7;
    int t = threadIdx.x;
    int f2 = t & 63;
    int p = t >> 6;
    int slice = part * 8 + p;                 // 0..63
    int s0 = gstart[g], s1 = gstart[g + 1];
    float sa = 0.f, sb = 0.f, qa = 0.f, qb = 0.f;
    for (int n = s0 + slice; n < s1; n += 64) {
        uint32_t u = A[(size_t)n * 64 + f2];
        float a = bf_lo(u), b = bf_hi(u);
        sa += a; qa += a * a;
        sb += b; qb += b * b;
    }
    L1[p][2 * f2] = sa; L1[p][2 * f2 + 1] = sb;
    L2[p][2 * f2] = qa; L2[p][2 * f2 + 1] = qb;
    __syncthreads();
    if (t < DIM) {
        float s = 0.f, s2 = 0.f;
#pragma unroll
        for (int i = 0; i < 8; i++) { s += L1[i][t]; s2 += L2[i][t]; }
        if (s != 0.f)  atomicAdd(&gsum[g * DIM + t], s);
        if (s2 != 0.f) atomicAdd(&gsqs[g * DIM + t], s2);
    }
}

// finalize stats: amean/rstd from accumulated sums; re-zero accumulators
// for the next layer's k_stats_part.
__global__ __launch_bounds__(128) void k_stats_fin(const int* __restrict__ gstart,
                                                   const float* __restrict__ mscale,
                                                   float* __restrict__ gsum, float* __restrict__ gsqs,
                                                   float* __restrict__ amean, float* __restrict__ rstd) {
    int g = blockIdx.x, t = threadIdx.x;
    int cnt = gstart[g + 1] - gstart[g];
    float inv = (cnt > 0) ? 1.0f / (float)cnt : 0.f;
    float s = gsum[g * DIM + t], s2 = gsqs[g * DIM + t];
    gsum[g * DIM + t] = 0.f;
    gsqs[g * DIM + t] = 0.f;
    float m = s * inv;
    float a = mscale[t];
    float var = s2 * inv - (2.f * a - a * a) * m * m;
    amean[g * DIM + t] = a * m;
    rstd[g * DIM + t] = rsqrtf(var + EPSV);
}

// final-layer norm+ELU+residual + x write + partial pool sums (8 blocks/graph).
__global__ __launch_bounds__(512) void k_norm_pool(const uint32_t* __restrict__ A,
                                                   const uint32_t* __restrict__ resb,
                                                   const int* __restrict__ gstart,
                                                   const float* __restrict__ amean, const float* __restrict__ rstd,
                                                   const float* __restrict__ gw, const float* __restrict__ gb,
                                                   float* __restrict__ outx, float* __restrict__ pooled) {
    __shared__ float L[8][DIM];
    int g = blockIdx.x >> 3;
    int part = blockIdx.x & 7;
    int t = threadIdx.x;
    int f2 = t & 63;
    int p = t >> 6;
    int slice = part * 8 + p;                 // 0..63
    int s0 = gstart[g], s1 = gstart[g + 1];
    float am0 = amean[g * DIM + 2 * f2], am1 = amean[g * DIM + 2 * f2 + 1];
    float rs0 = rstd[g * DIM + 2 * f2],  rs1 = rstd[g * DIM + 2 * f2 + 1];
    float w0_ = gw[2 * f2], w1_ = gw[2 * f2 + 1];
    float b0_ = gb[2 * f2], b1_ = gb[2 * f2 + 1];
    float p0 = 0.f, p1 = 0.f;
    for (int n = s0 + slice; n < s1; n += 64) {
        uint32_t u = A[(size_t)n * 64 + f2];
        uint32_t ur = resb[(size_t)n * 64 + f2];
        float a = bf_lo(u), b = bf_hi(u);
        float r0 = bf_lo(ur), r1 = bf_hi(ur);
        float o0 = w0_ * (a - am0) * rs0 + b0_;
        float o1 = w1_ * (b - am1) * rs1 + b1_;
        o0 = ((o0 > 0.f) ? o0 : elu_neg(o0)) + r0;
        o1 = ((o1 > 0.f) ? o1 : elu_neg(o1)) + r1;
        ((float2*)(outx + (size_t)n * DIM))[f2] = make_float2(o0, o1);
        p0 += o0; p1 += o1;
    }
    L[p][2 * f2] = p0; L[p][2 * f2 + 1] = p1;
    __syncthreads();
    if (t < DIM) {
        float s = 0.f;
#pragma unroll
        for (int i = 0; i < 8; i++) s += L[i][t];
        if (s != 0.f) atomicAdd(&pooled[g * DIM + t], s);
    }
}

// dense head from pooled sums: 128 blocks x 128 threads (tiny)
__global__ __launch_bounds__(128) void k_head(const float* __restrict__ pooled,
                                              const float* __restrict__ w1, const float* __restrict__ b1,
                                              const float* __restrict__ gamma, const float* __restrict__ beta,
                                              const float* __restrict__ rmean, const float* __restrict__ rvar,
                                              const float* __restrict__ w2, const float* __restrict__ b2,
                                              float* __restrict__ zout) {
    __shared__ float sz[DIM];
    int g = blockIdx.x, t = threadIdx.x;
    const float* sp = pooled + g * DIM;
    float acc = b1[t];
#pragma unroll 8
    for (int k = 0; k < DIM; k++) acc += sp[k] * w1[k * DIM + t];
    acc = gamma[t] * (acc - rmean[t]) * rsqrtf(rvar[t] + EPSV) + beta[t];
    sz[t] = fmaxf(acc, 0.f);
    __syncthreads();
    if (t < NCLS) {
        float a2 = b2[t];
#pragma unroll 8
        for (int k = 0; k < DIM; k++) a2 += sz[k] * w2[k * NCLS + t];
        zout[g * NCLS + t] = a2;
    }
}

// ---------------- launch ----------------

extern "C" void kernel_launch(void* const* d_in, const int* in_sizes, int n_in,
                              void* d_out, int out_size, void* d_ws, size_t ws_size,
                              hipStream_t stream) {
    const float* x_in   = (const float*)d_in[0];
    const int*   ei     = (const int*)d_in[1];
    const int*   batch  = (const int*)d_in[2];
    const float* conv_w = (const float*)d_in[3];
    const float* conv_b = (const float*)d_in[4];
    const float* gn_w   = (const float*)d_in[5];
    const float* gn_b   = (const float*)d_in[6];
    const float* gn_ms  = (const float*)d_in[7];
    const float* w1     = (const float*)d_in[8];
    const float* b1     = (const float*)d_in[9];
    const float* bng    = (const float*)d_in[10];
    const float* bnb    = (const float*)d_in[11];
    const float* bnm    = (const float*)d_in[12];
    const float* bnv    = (const float*)d_in[13];
    const float* w2     = (const float*)d_in[14];
    const float* b2     = (const float*)d_in[15];

    float* out_x = (float*)d_out;
    float* out_z = out_x + (size_t)N_NODES * DIM;

    char* ws = (char*)d_ws;
    size_t off = 0;
    auto alloc = [&](size_t bytes) -> void* {
        void* p = ws + off;
        off += (bytes + 255) / 256 * 256;
        return p;
    };
    uint8_t* h8      = (uint8_t*)alloc(sizeof(uint8_t) * (size_t)N_PAD * 128);    // int8 H (padded)
    float*   hsd     = (float*)alloc(sizeof(float) * (size_t)N_PAD);              // per-row scale*dis
    uint32_t* agg    = (uint32_t*)alloc(sizeof(uint32_t) * (size_t)N_NODES * 64); // bf16 agg
    uint32_t* resb   = (uint32_t*)alloc(sizeof(uint32_t) * (size_t)N_NODES * 64); // bf16 residual stream
    int2*  csc       = (int2*)alloc(sizeof(int2) * (size_t)N_EDGES);              // merged (src, w) — overflow only
    int2*  binned    = (int2*)alloc(sizeof(int2) * (size_t)N_EDGES);              // pass-1 bins (src, dst)
    int*   psrc      = (int*)alloc(sizeof(int) * (size_t)N_NODES * NSLOT);        // fixed 32-slot padded srcs
    uint32_t* wt     = (uint32_t*)alloc(sizeof(uint32_t) * NLAYERS * DIM * 64);   // bf16 W^T
    float* dis       = (float*)alloc(sizeof(float) * N_NODES);
    int*   rowoff    = (int*)alloc(sizeof(int) * (N_NODES + 1));
    int*   bcnt      = (int*)alloc(sizeof(int) * NBUCKET);
    int*   boffb     = (int*)alloc(sizeof(int) * (NBUCKET + 1));
    int*   bcur      = (int*)alloc(sizeof(int) * NBUCKET);
    int*   gstart    = (int*)alloc(sizeof(int) * (NGRAPH + 1));
    float* amean     = (float*)alloc(sizeof(float) * NGRAPH * DIM);
    float* rstd      = (float*)alloc(sizeof(float) * NGRAPH * DIM);
    float* pooled    = (float*)alloc(sizeof(float) * NGRAPH * DIM);
    float* gsum      = (float*)alloc(sizeof(float) * NGRAPH * DIM);
    float* gsqs      = (float*)alloc(sizeof(float) * NGRAPH * DIM);

    // ---- prepass ----
    k_node_meta<<<(N_NODES + 255) / 256, 256, 0, stream>>>(batch, gstart, bcnt, pooled, gsum, gsqs);
    k_bhist<<<P1_BLOCKS, 256, 0, stream>>>(ei, bcnt);
    k_bscan<<<1, 256, 0, stream>>>(bcnt, boffb, bcur);
    k_bin_edges<<<P1_BLOCKS, 256, 0, stream>>>(ei, bcur, binned);
    k_bucket_build<<<NBUCKET, 256, 0, stream>>>(binned, boffb, rowoff, dis, psrc);
    k_scatter<<<NBUCKET, 256, 0, stream>>>(binned, dis, rowoff, boffb, csc, psrc);
    k_cast_w<<<(NLAYERS * DIM * 64 + 255) / 256, 256, 0, stream>>>(conv_w, wt);

    // ---- layers ----
    k_gemm0<<<N_PAD / 64, 256, 0, stream>>>(x_in, wt, h8, hsd, dis);
    for (int l = 0; l < NLAYERS; l++) {
        k_aggregate<<<N_NODES / 8, 256, 0, stream>>>(h8, hsd, psrc, csc, rowoff, dis,
                                                     conv_b + (size_t)l * DIM, agg);
        k_stats_part<<<NGRAPH * POOL_PARTS, 512, 0, stream>>>(agg, gstart, gsum, gsqs);
        k_stats_fin<<<NGRAPH, 128, 0, stream>>>(gstart, gn_ms + (size_t)l * DIM, gsum, gsqs, amean, rstd);
        if (l == 0) {
            k_norm_gemm<false><<<N_PAD / 64, 256, 0, stream>>>(agg, batch, amean, rstd, gn_w, gn_b,
                                                               (const void*)x_in, resb,
                                                               wt + (size_t)1 * DIM * 64, h8, hsd, dis);
        } else if (l < NLAYERS - 1) {
            k_norm_gemm<true><<<N_PAD / 64, 256, 0, stream>>>(agg, batch, amean, rstd,
                                                              gn_w + (size_t)l * DIM, gn_b + (size_t)l * DIM,
                                                              (const void*)resb, resb,
                                                              wt + (size_t)(l + 1) * DIM * 64, h8, hsd, dis);
        } else {
            k_norm_pool<<<NGRAPH * POOL_PARTS, 512, 0, stream>>>(agg, resb, gstart, amean, rstd,
                                                                 gn_w + (size_t)l * DIM, gn_b + (size_t)l * DIM,
                                                                 out_x, pooled);
            k_head<<<NGRAPH, 128, 0, stream>>>(pooled, w1, b1, bng, bnb, bnm, bnv, w2, b2, out_z);
        }
    }
}